// Round 5
// baseline (99.991 us; speedup 1.0000x reference)
//
#include <hip/hip_runtime.h>

// Chamfer loss: B=8, P=32, N=M=1024, fp32 in, scalar fp32 out.
// Reference quirk: x[bp,m,c] = rp[bp, (3m+c)%M, (3m+c)>>10]  (torch permute+reshape).
//
// R9: R8 + two changes aimed at the SAME diagnosis (AGPR-resident min state):
//  1. rmin kept as two f32x16 vectors passed through an empty asm
//     ("+v" constraints) every iteration -> register allocator MUST keep them
//     in arch VGPRs; the 32 fmin/iter become plain v_min_f32 instead of
//     accvgpr_read + v_min + accvgpr_write triples (the ~2.5x VALU inflation
//     seen in R6-R8: VALUBusy 62% ~= 41K cyc/SIMD vs ~16.6K source-level).
//  2. Both stripes' MFMAs fused into one asm block (acc0+acc1 live): the acc1
//     pair covers 16 of acc0's 18 post-MFMA wait states; one shared nop tail
//     (7+7+1) protects both. Saves ~20 nop cycles/iter vs R8.
// Register budget: af 8 + bf/nb 16 + Z 16 + acc 32 + rmin 32 + misc ~= 116
// arch VGPRs < 128 (4 waves/EU, which LDS already caps).
//
// Numerics (unchanged, bit-exact vs fp32 reference): dist = xx + yy - 2x.y via
// 3-way bf16 split (h0+h1+h2), 30 K-slots, 2x mfma_f32_32x32x16_bf16 per 32x32
// tile. 1024 threads / 16 waves; wave owns 64 rows = 2 stripes; 32 N-tiles.
// Row-min: rmin regs + DPP ror(1,2,4,8) + swizzle xor16.
// Col-min: min3 tree + bpermute xor32 + colW[16][1024] overlay on dead A panel.

#define MM 1024
#define NN 1024
#define THREADS 1024
#define NWAVES 16
#define FINF 3.4e38f

typedef float f32x16 __attribute__((ext_vector_type(16)));
typedef __bf16 bf16x8 __attribute__((ext_vector_type(8)));

#define B_STRIDE 80                       // bytes per y-column (40 ushort slots)
#define A_STRIDE 64                       // bytes per x-row (32 ushort slots)
#define B_OFF 0
#define A_OFF (NN * B_STRIDE)             // 81920
#define CW_OFF A_OFF                      // overlay: colW[16][1024] f32 = 64KB
#define RS_OFF (A_OFF + MM * A_STRIDE)    // 147456
#define RED_OFF (RS_OFF + 128)            // 32 rowsum slots
#define LDS_BYTES (RED_OFF + 64)          // 147648

__device__ __forceinline__ unsigned short bf16_rne(float v) {
    unsigned u = __float_as_uint(v);
    u = u + 0x7FFFu + ((u >> 16) & 1u);
    return (unsigned short)(u >> 16);
}
__device__ __forceinline__ float bf16f(unsigned short h) {
    return __uint_as_float(((unsigned)h) << 16);
}
struct S3 { unsigned short h0, h1, h2; };
__device__ __forceinline__ S3 split3(float v) {
    S3 o;
    o.h0 = bf16_rne(v);
    float r = v - bf16f(o.h0);
    o.h1 = bf16_rne(r);
    float r2 = r - bf16f(o.h1);
    o.h2 = bf16_rne(r2);
    return o;
}
__device__ __forceinline__ unsigned pk(unsigned short a, unsigned short b) {
    return (unsigned)a | ((unsigned)b << 16);
}
__device__ __forceinline__ float min3f(float a, float b, float c) {
    return fminf(fminf(a, b), c);   // folds to v_min3_f32
}
template <int CTRL>
__device__ __forceinline__ float dpp_ror_min(float v) {
    int vi = __float_as_int(v);
    int t  = __builtin_amdgcn_update_dpp(vi, vi, CTRL, 0xf, 0xf, true);
    return fminf(v, __int_as_float(t));
}

__global__ __launch_bounds__(THREADS)
__attribute__((amdgpu_waves_per_eu(4, 4)))
void chamfer_kernel(const float* __restrict__ nrf,   // (BP, N, 3) -> y
                    const float* __restrict__ rp,    // (BP, M, 3) -> x (scrambled)
                    float* __restrict__ out,
                    float inv_bpm, float inv_bpn) {
    __shared__ __align__(16) unsigned char smem[LDS_BYTES];
    unsigned char* Bb = smem + B_OFF;
    unsigned short* As = (unsigned short*)(smem + A_OFF);
    float* colW = (float*)(smem + CW_OFF);
    float* rowsumS = (float*)(smem + RS_OFF);
    float* redS = (float*)(smem + RED_OFF);

    const int bp = blockIdx.x;
    const int tid = threadIdx.x;
    const int lane = tid & 63;
    const int wave = tid >> 6;
    const int l31 = lane & 31;
    const int lh = lane >> 5;
    const unsigned short ONE = 0x3F80;

    const float* yB = nrf + (size_t)bp * NN * 3;
    const float* xB = rp + (size_t)bp * MM * 3;

    // ---- B panel: per col slots (b = y split, q = yy split)
    {
        const int c = tid;
        float y0 = yB[c * 3 + 0], y1 = yB[c * 3 + 1], y2 = yB[c * 3 + 2];
        float yy = __builtin_fmaf(y0, y0, __builtin_fmaf(y1, y1, y2 * y2));
        S3 b0 = split3(y0), b1 = split3(y1), b2 = split3(y2), q = split3(yy);
        uint4* dst = (uint4*)(Bb + c * B_STRIDE);
        dst[0] = make_uint4(pk(b0.h0, b0.h1), pk(b0.h0, b0.h1), pk(b0.h2, b0.h0), pk(b1.h0, b1.h1));
        dst[1] = make_uint4(pk(b1.h0, b1.h1), pk(b1.h2, b1.h0), pk(b2.h0, b2.h1), pk(b2.h0, b2.h1));
        dst[2] = make_uint4(pk(b2.h2, b2.h0), pk(ONE, ONE), pk(ONE, q.h0), pk(q.h1, q.h2));
        dst[3] = make_uint4(pk(b0.h2, b0.h1), pk(b1.h2, b1.h1), pk(b2.h2, b2.h1), 0u);
        dst[4] = make_uint4(0u, 0u, 0u, 0u);
    }
    // ---- A panel: per row slots (a = -2x split, p = xx split)
    {
        const int m = tid;
        int k = 3 * m;
        float x0 = xB[((k    ) & (MM - 1)) * 3 + ((k    ) >> 10)];
        float x1 = xB[((k + 1) & (MM - 1)) * 3 + ((k + 1) >> 10)];
        float x2 = xB[((k + 2) & (MM - 1)) * 3 + ((k + 2) >> 10)];
        float xx = __builtin_fmaf(x0, x0, __builtin_fmaf(x1, x1, x2 * x2));
        S3 a0 = split3(-2.0f * x0), a1 = split3(-2.0f * x1), a2 = split3(-2.0f * x2);
        S3 p = split3(xx);
        uint4* dst = (uint4*)((unsigned char*)As + m * A_STRIDE);
        dst[0] = make_uint4(pk(a0.h0, a0.h0), pk(a0.h1, a0.h1), pk(a0.h0, a0.h2), pk(a1.h0, a1.h0));
        dst[1] = make_uint4(pk(a1.h1, a1.h1), pk(a1.h0, a1.h2), pk(a2.h0, a2.h0), pk(a2.h1, a2.h1));
        dst[2] = make_uint4(pk(a2.h0, a2.h2), pk(p.h0, p.h1), pk(p.h2, ONE), pk(ONE, ONE));
        dst[3] = make_uint4(pk(a0.h1, a0.h2), pk(a1.h1, a1.h2), pk(a2.h1, a2.h2), 0u);
    }
    __syncthreads();

    // ---- A-fragment loads (once; rows fixed per wave): 2 stripes x 2 K-halves
    const int m0 = wave * 64;
    bf16x8 af[2][2];
    #pragma unroll
    for (int s = 0; s < 2; ++s) {
        #pragma unroll
        for (int h = 0; h < 2; ++h)
            af[s][h] = *(const bf16x8*)(As + (m0 + s * 32 + l31) * 32 + h * 16 + lh * 8);
    }
    __syncthreads();   // after this, A panel is colW

    f32x16 rmin0, rmin1;
    #pragma unroll
    for (int j = 0; j < 16; ++j) { rmin0[j] = FINF; rmin1[j] = FINF; }

    f32x16 Z = {};
    const unsigned char* bptr = Bb + l31 * B_STRIDE + lh * 16;
    const int xaddr32 = (lane ^ 32) << 2;
    float* colWrow = colW + wave * 1024;

    bf16x8 bf0 = *(const bf16x8*)(bptr);
    bf16x8 bf1 = *(const bf16x8*)(bptr + 32);
    for (int t = 0; t < 32; ++t) {
        // prefetch next tile's B-frags (last iter reads dead LDS, values unused)
        const unsigned char* np = bptr + 32 * B_STRIDE;
        bf16x8 nb0 = *(const bf16x8*)(np);
        bf16x8 nb1 = *(const bf16x8*)(np + 32);

        // Both stripes in one asm block, arch-VGPR accumulators.
        // s_nop 1: VALU-write(bf rotation movs)->MFMA-read, 2 states.
        // acc0's post-write hazard: covered by the 2 acc1 MFMAs (16) + tail.
        // acc1's post-write hazard: s_nop 7+7+1 = 18 states.
        f32x16 acc0, acc1;
        asm("s_nop 1\n\t"
            "v_mfma_f32_32x32x16_bf16 %0, %2, %4, %6\n\t"
            "v_mfma_f32_32x32x16_bf16 %0, %3, %5, %0\n\t"
            "v_mfma_f32_32x32x16_bf16 %1, %7, %4, %6\n\t"
            "v_mfma_f32_32x32x16_bf16 %1, %8, %5, %1\n\t"
            "s_nop 7\n\t"
            "s_nop 7\n\t"
            "s_nop 1"
            : "=&v"(acc0), "=&v"(acc1)
            : "v"(af[0][0]), "v"(af[0][1]), "v"(bf0), "v"(bf1), "v"(Z),
              "v"(af[1][0]), "v"(af[1][1]));

        #pragma unroll
        for (int j = 0; j < 16; ++j) rmin0[j] = fminf(rmin0[j], acc0[j]);
        #pragma unroll
        for (int j = 0; j < 16; ++j) rmin1[j] = fminf(rmin1[j], acc1[j]);
        // Pin rmin to arch VGPRs (empty asm, zero instructions): the fmin
        // results above must live in "v"-class regs -> no accvgpr round-trips.
        asm("" : "+v"(rmin0), "+v"(rmin1));

        float u0 = min3f(acc0[0], acc0[1], acc0[2]);
        float u1 = min3f(acc0[3], acc0[4], acc0[5]);
        float u2 = min3f(acc0[6], acc0[7], acc0[8]);
        float u3 = min3f(acc0[9], acc0[10], acc0[11]);
        float u4 = min3f(acc0[12], acc0[13], acc0[14]);
        float cm = fminf(min3f(u0, u1, u2), min3f(u3, u4, acc0[15]));
        u0 = min3f(acc1[0], acc1[1], acc1[2]);
        u1 = min3f(acc1[3], acc1[4], acc1[5]);
        u2 = min3f(acc1[6], acc1[7], acc1[8]);
        u3 = min3f(acc1[9], acc1[10], acc1[11]);
        u4 = min3f(acc1[12], acc1[13], acc1[14]);
        cm = fminf(cm, fminf(min3f(u0, u1, u2), min3f(u3, u4, acc1[15])));

        // merge the two lane-halves -> full 64-row col-min for this wave
        int pz = __builtin_amdgcn_ds_bpermute(xaddr32, __float_as_int(cm));
        cm = fminf(cm, __int_as_float(pz));
        if (lh == 0) colWrow[t * 32 + l31] = cm;

        bf0 = nb0; bf1 = nb1; bptr = np;
    }

    // ---- row-min reduce: min over lanes 0..31 (cols) per half; rows = f(j,s,lh)
    float rowsum = 0.0f;
    #pragma unroll
    for (int s = 0; s < 2; ++s) {
        #pragma unroll
        for (int j = 0; j < 16; ++j) {
            float v = (s == 0) ? rmin0[j] : rmin1[j];
            v = dpp_ror_min<0x121>(v);   // row_ror:1
            v = dpp_ror_min<0x122>(v);   // row_ror:2
            v = dpp_ror_min<0x124>(v);   // row_ror:4
            v = dpp_ror_min<0x128>(v);   // row_ror:8 -> per-16 min
            int sw = __builtin_amdgcn_ds_swizzle(__float_as_int(v), 0x401F); // xor16
            v = fminf(v, __int_as_float(sw));
            rowsum += v;                 // each (s,j,lh) is a distinct row
        }
    }
    if (l31 == 0) rowsumS[wave * 2 + lh] = rowsum;
    __syncthreads();

    // ---- cross-wave col-min merge + column sum (1 col per thread)
    {
        const int c = tid;
        float v = colW[c];
        #pragma unroll
        for (int w = 1; w < NWAVES; ++w) v = fminf(v, colW[w * 1024 + c]);
        float csum = v;
        #pragma unroll
        for (int off = 32; off > 0; off >>= 1) csum += __shfl_xor(csum, off, 64);
        if (lane == 0) redS[wave] = csum;
    }
    __syncthreads();

    if (tid == 0) {
        float rs = 0.0f, cs = 0.0f;
        #pragma unroll
        for (int w = 0; w < NWAVES; ++w) cs += redS[w];
        #pragma unroll
        for (int w = 0; w < 2 * NWAVES; ++w) rs += rowsumS[w];
        atomicAdd(out, rs * inv_bpm + cs * inv_bpn);
    }
}

extern "C" void kernel_launch(void* const* d_in, const int* in_sizes, int n_in,
                              void* d_out, int out_size, void* d_ws, size_t ws_size,
                              hipStream_t stream) {
    const float* nrf = (const float*)d_in[0];  // (B,P,N,3)
    const float* rp  = (const float*)d_in[1];  // (B,P,M,3)
    float* out = (float*)d_out;

    const int BP = in_sizes[1] / (MM * 3);     // 256
    const float inv_bpm = 1.0f / (float)(BP * MM);
    const float inv_bpn = 1.0f / (float)(BP * NN);

    (void)hipMemsetAsync(out, 0, sizeof(float), stream);
    chamfer_kernel<<<BP, THREADS, 0, stream>>>(nrf, rp, out, inv_bpm, inv_bpn);
}

// Round 6
// 89.455 us; speedup vs baseline: 1.1178x; 1.1178x over previous
//
#include <hip/hip_runtime.h>

// Chamfer loss: B=8, P=32, N=M=1024, fp32 in, scalar fp32 out.
// Reference quirk: x[bp,m,c] = rp[bp, (3m+c)%M, (3m+c)>>10]  (torch permute+reshape).
//
// R10: occupancy-first restructure. R5-R9 were latency-bound at 4 waves/SIMD
// (148KB LDS -> 1 block/CU) with long per-iter dependence chains; all register
// interventions were null (gfx950 VALU reads AGPRs directly - the inflation
// theory was wrong). New shape:
//  - mfma_f32_16x16x32_bf16: the 30-slot fp32-emulation scheme fits K=32 in
//    ONE MFMA (no acc chaining), acc = 4 regs, rmin = 4 regs/stripe.
//  - 512 blocks (bp = blk>>1, row-half = blk&1) x 1024 thr (16 waves); wave
//    owns 32 rows = 2 stripes of 16. Per-wave state ~50 VGPR -> 8 waves/SIMD.
//  - LDS 73.8KB -> 2 blocks/CU = 32 waves/CU: B panel tile-packed
//    [64 t][16 c][64B] = 64KB; a wave's b128 frag read is 1KB contiguous =
//    conflict-free. A-frags built directly from global (no A panel).
//  - col-min: per-tile lane min3 + xor16 swizzle merge, then native ds_min_u32
//    (ordered-uint key) into colK[2][1024] (8KB); block result -> colP[blk][1024]
//    in workspace (2MB); kernel2 merges halves + sums. Row-min: DPP ror within
//    16 + xor16/xor32 sum, per-block atomicAdd.

#define MM 1024
#define NN 1024
#define THREADS 1024
#define NWAVES 16
#define FINF 3.4e38f

typedef float f32x4 __attribute__((ext_vector_type(4)));
typedef __bf16 bf16x8 __attribute__((ext_vector_type(8)));

#define BT_OFF 0                      // B tiles: 64 x 1KB = 65536
#define CK_OFF 65536                  // colK[2][1024] u32 = 8192
#define RS_OFF (CK_OFF + 8192)        // rowsumS[16]
#define LDS_BYTES (RS_OFF + 64)       // 73792 <= 81920 -> 2 blocks/CU

__device__ __forceinline__ unsigned short bf16_rne(float v) {
    unsigned u = __float_as_uint(v);
    u = u + 0x7FFFu + ((u >> 16) & 1u);
    return (unsigned short)(u >> 16);
}
__device__ __forceinline__ float bf16f(unsigned short h) {
    return __uint_as_float(((unsigned)h) << 16);
}
struct S3 { unsigned short h0, h1, h2; };
__device__ __forceinline__ S3 split3(float v) {
    S3 o;
    o.h0 = bf16_rne(v);
    float r = v - bf16f(o.h0);
    o.h1 = bf16_rne(r);
    float r2 = r - bf16f(o.h1);
    o.h2 = bf16_rne(r2);
    return o;
}
__device__ __forceinline__ unsigned pk(unsigned short a, unsigned short b) {
    return (unsigned)a | ((unsigned)b << 16);
}
__device__ __forceinline__ float min3f(float a, float b, float c) {
    return fminf(fminf(a, b), c);   // folds to v_min3_f32
}
template <int CTRL>
__device__ __forceinline__ float dpp_ror_min(float v) {
    int vi = __float_as_int(v);
    int t  = __builtin_amdgcn_update_dpp(vi, vi, CTRL, 0xf, 0xf, true);
    return fminf(v, __int_as_float(t));
}
// Order-preserving float->uint key (handles tiny negative dists) and inverse.
__device__ __forceinline__ unsigned fkey(float v) {
    unsigned u = __float_as_uint(v);
    return ((int)u < 0) ? ~u : (u | 0x80000000u);
}
__device__ __forceinline__ float unkey(unsigned k) {
    return ((int)k < 0) ? __uint_as_float(k & 0x7FFFFFFFu) : __uint_as_float(~k);
}

__global__ __launch_bounds__(THREADS, 8)
void chamfer_main(const float* __restrict__ nrf,   // (BP, N, 3) -> y
                  const float* __restrict__ rp,    // (BP, M, 3) -> x (scrambled)
                  float* __restrict__ colP,        // (2*BP, 1024) workspace
                  float* __restrict__ out,
                  float inv_bpm) {
    __shared__ __align__(16) unsigned char smem[LDS_BYTES];
    unsigned* colK = (unsigned*)(smem + CK_OFF);
    float* rowsumS = (float*)(smem + RS_OFF);

    const int bp   = blockIdx.x >> 1;
    const int half = blockIdx.x & 1;
    const int tid  = threadIdx.x;
    const int lane = tid & 63;
    const int wave = tid >> 6;
    const int l15  = lane & 15;
    const int g    = lane >> 4;        // k-chunk / row-group id (0..3)
    const unsigned short ONE = 0x3F80;

    const float* yB = nrf + (size_t)bp * NN * 3;
    const float* xB = rp + (size_t)bp * MM * 3;

    // ---- B panel: col c's 32 slots, tile-packed [c>>4][c&15][4 x uint4]
    {
        const int c = tid;
        float y0 = yB[c * 3 + 0], y1 = yB[c * 3 + 1], y2 = yB[c * 3 + 2];
        float yy = __builtin_fmaf(y0, y0, __builtin_fmaf(y1, y1, y2 * y2));
        S3 b0 = split3(y0), b1 = split3(y1), b2 = split3(y2), q = split3(yy);
        uint4* dst = (uint4*)(smem + BT_OFF + (c >> 4) * 1024 + (c & 15) * 64);
        dst[0] = make_uint4(pk(b0.h0, b0.h1), pk(b0.h0, b0.h1), pk(b0.h2, b0.h0), pk(b1.h0, b1.h1));
        dst[1] = make_uint4(pk(b1.h0, b1.h1), pk(b1.h2, b1.h0), pk(b2.h0, b2.h1), pk(b2.h0, b2.h1));
        dst[2] = make_uint4(pk(b2.h2, b2.h0), pk(ONE, ONE), pk(ONE, q.h0), pk(q.h1, q.h2));
        dst[3] = make_uint4(pk(b0.h2, b0.h1), pk(b1.h2, b1.h1), pk(b2.h2, b2.h1), 0u);
        // colK init (sentinel >= every real key)
        colK[c] = 0xFFFFFFFFu;
        colK[1024 + c] = 0xFFFFFFFFu;
    }

    // ---- A-fragments directly from global: stripe s row = half*512 + wave*32
    //      + s*16 + l15; lane takes slot-uints [g*4 .. g*4+4).
    bf16x8 af[2];
    #pragma unroll
    for (int s = 0; s < 2; ++s) {
        const int m = half * 512 + wave * 32 + s * 16 + l15;
        const int k = 3 * m;
        float x0 = xB[((k    ) & (MM - 1)) * 3 + ((k    ) >> 10)];
        float x1 = xB[((k + 1) & (MM - 1)) * 3 + ((k + 1) >> 10)];
        float x2 = xB[((k + 2) & (MM - 1)) * 3 + ((k + 2) >> 10)];
        float xx = __builtin_fmaf(x0, x0, __builtin_fmaf(x1, x1, x2 * x2));
        S3 a0 = split3(-2.0f * x0), a1 = split3(-2.0f * x1), a2 = split3(-2.0f * x2);
        S3 p = split3(xx);
        uint4 q0 = make_uint4(pk(a0.h0, a0.h0), pk(a0.h1, a0.h1), pk(a0.h0, a0.h2), pk(a1.h0, a1.h0));
        uint4 q1 = make_uint4(pk(a1.h1, a1.h1), pk(a1.h0, a1.h2), pk(a2.h0, a2.h0), pk(a2.h1, a2.h1));
        uint4 q2 = make_uint4(pk(a2.h0, a2.h2), pk(p.h0, p.h1), pk(p.h2, ONE), pk(ONE, ONE));
        uint4 q3 = make_uint4(pk(a0.h1, a0.h2), pk(a1.h1, a1.h2), pk(a2.h1, a2.h2), 0u);
        uint4 sel = (g == 0) ? q0 : (g == 1) ? q1 : (g == 2) ? q2 : q3;  // cndmask chain
        union { uint4 u; bf16x8 b; } cv; cv.u = sel;
        af[s] = cv.b;
    }
    __syncthreads();

    // ---- main loop: 64 col-tiles, 2 stripes each; all-immediate addressing.
    const unsigned fragoff = (unsigned)((l15 * 4 + g) * 16);   // byte off in tile
    const unsigned char* BtBase = smem + BT_OFF;
    unsigned* colKme = colK + (lane >> 5) * 1024 + l15;        // +t*16 per tile
    const f32x4 Z = {0.0f, 0.0f, 0.0f, 0.0f};

    float rmin0[4], rmin1[4];
    #pragma unroll
    for (int j = 0; j < 4; ++j) { rmin0[j] = FINF; rmin1[j] = FINF; }

    bf16x8 bfc = *(const bf16x8*)(BtBase + fragoff);
    #pragma unroll
    for (int t = 0; t < 64; ++t) {
        // prefetch next tile (t=63 reads colK region: in-bounds, unused)
        bf16x8 bfn = *(const bf16x8*)(BtBase + (t + 1) * 1024 + fragoff);

        f32x4 acc0 = __builtin_amdgcn_mfma_f32_16x16x32_bf16(af[0], bfc, Z, 0, 0, 0);
        f32x4 acc1 = __builtin_amdgcn_mfma_f32_16x16x32_bf16(af[1], bfc, Z, 0, 0, 0);

        #pragma unroll
        for (int j = 0; j < 4; ++j) rmin0[j] = fminf(rmin0[j], acc0[j]);
        #pragma unroll
        for (int j = 0; j < 4; ++j) rmin1[j] = fminf(rmin1[j], acc1[j]);

        float cm0 = fminf(min3f(acc0[0], acc0[1], acc0[2]), acc0[3]);
        float cm1 = fminf(min3f(acc1[0], acc1[1], acc1[2]), acc1[3]);
        float cm = fminf(cm0, cm1);
        // merge row-groups g<->g^1 (lanes l^16), then ds_min merges the rest
        int sw = __builtin_amdgcn_ds_swizzle(__float_as_int(cm), 0x401F);
        cm = fminf(cm, __int_as_float(sw));
        atomicMin(colKme + t * 16, fkey(cm));   // ds_min_u32, native

        bfc = bfn;
    }

    // ---- row-min: min over cols = over l15 (DPP ror within 16-lane rows).
    float rowsum = 0.0f;
    #pragma unroll
    for (int s = 0; s < 2; ++s) {
        #pragma unroll
        for (int j = 0; j < 4; ++j) {
            float v = (s == 0) ? rmin0[j] : rmin1[j];
            v = dpp_ror_min<0x121>(v);
            v = dpp_ror_min<0x122>(v);
            v = dpp_ror_min<0x124>(v);
            v = dpp_ror_min<0x128>(v);   // min over the 16 lanes of group g
            rowsum += v;                 // row = s*16 + g*4 + j
        }
    }
    // sum across the 4 groups: xor16 (swizzle) + xor32 (bpermute)
    rowsum += __int_as_float(__builtin_amdgcn_ds_swizzle(__float_as_int(rowsum), 0x401F));
    rowsum += __int_as_float(__builtin_amdgcn_ds_bpermute((lane ^ 32) << 2, __float_as_int(rowsum)));
    if (lane == 0) rowsumS[wave] = rowsum;
    __syncthreads();

    // ---- block epilogue: col partials -> workspace; rowsum -> out
    {
        unsigned k0 = colK[tid], k1 = colK[1024 + tid];
        colP[(size_t)blockIdx.x * 1024 + tid] = unkey(k0 < k1 ? k0 : k1);
    }
    if (tid < 64) {
        float r = (tid < 16) ? rowsumS[tid] : 0.0f;
        #pragma unroll
        for (int off = 8; off > 0; off >>= 1) r += __shfl_xor(r, off, 64);
        if (tid == 0) atomicAdd(out, r * inv_bpm);
    }
}

__global__ __launch_bounds__(1024)
void chamfer_reduce(const float* __restrict__ colP, float* __restrict__ out,
                    float inv_bpn) {
    const int bp = blockIdx.x;
    const int tid = threadIdx.x;
    const int lane = tid & 63;
    const int wave = tid >> 6;
    __shared__ float ws[16];

    float v = fminf(colP[(size_t)(2 * bp) * 1024 + tid],
                    colP[(size_t)(2 * bp + 1) * 1024 + tid]);
    #pragma unroll
    for (int off = 32; off > 0; off >>= 1) v += __shfl_xor(v, off, 64);
    if (lane == 0) ws[wave] = v;
    __syncthreads();
    if (tid == 0) {
        float s = 0.0f;
        #pragma unroll
        for (int w = 0; w < 16; ++w) s += ws[w];
        atomicAdd(out, s * inv_bpn);
    }
}

extern "C" void kernel_launch(void* const* d_in, const int* in_sizes, int n_in,
                              void* d_out, int out_size, void* d_ws, size_t ws_size,
                              hipStream_t stream) {
    const float* nrf = (const float*)d_in[0];  // (B,P,N,3)
    const float* rp  = (const float*)d_in[1];  // (B,P,M,3)
    float* out = (float*)d_out;
    float* colP = (float*)d_ws;                // needs 2*BP*1024*4 = 2MB

    const int BP = in_sizes[1] / (MM * 3);     // 256
    const float inv_bpm = 1.0f / (float)(BP * MM);
    const float inv_bpn = 1.0f / (float)(BP * NN);

    (void)hipMemsetAsync(out, 0, sizeof(float), stream);
    chamfer_main<<<BP * 2, THREADS, 0, stream>>>(nrf, rp, colP, out, inv_bpm);
    chamfer_reduce<<<BP, 1024, 0, stream>>>(colP, out, inv_bpn);
}